// Round 10
// baseline (139.963 us; speedup 1.0000x reference)
//
#include <hip/hip_runtime.h>
#include <hip/hip_cooperative_groups.h>
#include <stdint.h>

namespace cg = cooperative_groups;

typedef __attribute__((ext_vector_type(8))) short short8;
typedef __attribute__((ext_vector_type(4))) float f32x4;

#define DEVI __device__ __forceinline__

DEVI ushort f2bf(float f) {
  union { float f; uint32_t u; } v; v.f = f;
  uint32_t r = v.u + 0x7fffu + ((v.u >> 16) & 1u);
  return (ushort)(r >> 16);
}

// HW packed f32->bf16 (RTNE, identical rounding to f2bf): 1 inst per 2 elems.
DEVI uint32_t cvtpk(float lo, float hi) {
  uint32_t r;
  asm("v_cvt_pk_bf16_f32 %0, %1, %2" : "=v"(r) : "v"(lo), "v"(hi));
  return r;
}
DEVI uint2 pack4(float a, float b, float c, float d) {
  uint2 o; o.x = cvtpk(a, b); o.y = cvtpk(c, d);
  return o;
}

#define LDA 72   // 144B LDS row stride -> conflict-free b128 reads

// LDS union: phase 1 (36.9 KB) / phase 2 (55.0 KB). 55 KB -> 2 blocks/CU,
// grid 512 = exactly chip capacity for the cooperative launch.
union SharedU {
  struct {
    ushort As[2][64 * LDA];
    ushort Bs[2][64 * LDA];
  } p1;
  struct {
    ushort As[2][16 * LDA];
    ushort Bs[2][128 * LDA];
    float h2f[16][132];
    float W3s[1280];
  } p2;
};

// ---------------------------------------------------------------------------
// Quantum sim collapses analytically (params provably dead):
//   feats per 2x2 patch (v0,v1,v2,v3) = [cos v0, cos v1, cos v0*cos v2,
//   cos v1*cos v3]; CNOT chains = linear bit map; RZ phases cancel in |.|^2.
//
// Single cooperative launch (no inter-dispatch drain/flush boundary):
//   Phase 1 (R9-champion geometry): h1 = relu(feats(x) @ W1^T + b1),
//     cos + W1 cast fused into dbuf staging. 512 blocks: bm=b&127, bn=b>>7.
//   grid.sync()
//   Phase 2: 512 blocks x 16-row strips (2 blocks/CU, 2x champion's
//     concurrency): h2 = relu(h1 @ W2^T + b2) in LDS -> head + log_softmax.
// ---------------------------------------------------------------------------
__global__ __launch_bounds__(256, 2) void fused_all(
    const float* __restrict__ x, const float* __restrict__ W1,
    const float* __restrict__ b1, const float* __restrict__ W2,
    const float* __restrict__ b2, const float* __restrict__ W3,
    const float* __restrict__ b3, ushort* __restrict__ h1,
    float* __restrict__ out) {
  __shared__ SharedU sh;

  const int tid = threadIdx.x;
  const int lane = tid & 63;
  const int w = tid >> 6, wm = w >> 1, wn = w & 1;

  // ======================= Phase 1 =======================
  {
    constexpr int NK = 13;    // K = 832 (784 + pad)
    const int bm = blockIdx.x & 127, bn = blockIdx.x >> 7;
    const int m0 = bm * 64, n0 = bn * 64;

    const int srow = tid >> 4;        // 0..15
    const int pl = tid & 15;          // patch slot / f32x4 slot
    const int kc4 = pl * 4;

    float2 atop[4], abot[4];
    float4 bw[4];

    f32x4 acc[2][2];
#pragma unroll
    for (int m = 0; m < 2; ++m)
#pragma unroll
      for (int n = 0; n < 2; ++n) {
        f32x4 z = {0.f, 0.f, 0.f, 0.f};
        acc[m][n] = z;
      }

    auto loadT = [&](int kt) {
      const int q = kt * 16 + pl;
      if (q < 196) {
        const int i = q / 14, j = q - i * 14;
        const float* px = x + i * 56 + j * 2;
#pragma unroll
        for (int c = 0; c < 4; ++c) {
          const float* p = px + (size_t)(m0 + c * 16 + srow) * 784;
          atop[c] = *(const float2*)p;
          abot[c] = *(const float2*)(p + 28);
        }
      }
      const int k0 = kt * 64;
      if (k0 + kc4 < 784) {
#pragma unroll
        for (int c = 0; c < 4; ++c)
          bw[c] = *(const float4*)(W1 + (size_t)(n0 + c * 16 + srow) * 784 + k0 + kc4);
      } else {
#pragma unroll
        for (int c = 0; c < 4; ++c) bw[c] = make_float4(0.f, 0.f, 0.f, 0.f);
      }
    };

    auto writeT = [&](int buf, int kt) {
      const int q = kt * 16 + pl;
      ushort* as = sh.p1.As[buf];
      ushort* bs = sh.p1.Bs[buf];
      if (q < 196) {
#pragma unroll
        for (int c = 0; c < 4; ++c) {
          float c0 = __cosf(atop[c].x), c1 = __cosf(atop[c].y);
          float c2 = __cosf(abot[c].x), c3 = __cosf(abot[c].y);
          *(uint2*)(as + (c * 16 + srow) * LDA + pl * 4) =
              pack4(c0, c1, c0 * c2, c1 * c3);
        }
      } else {
        uint2 z; z.x = 0; z.y = 0;
#pragma unroll
        for (int c = 0; c < 4; ++c)
          *(uint2*)(as + (c * 16 + srow) * LDA + pl * 4) = z;
      }
#pragma unroll
      for (int c = 0; c < 4; ++c)
        *(uint2*)(bs + (c * 16 + srow) * LDA + kc4) =
            pack4(bw[c].x, bw[c].y, bw[c].z, bw[c].w);
    };

    auto mma = [&](int buf) {
      const ushort* as = sh.p1.As[buf];
      const ushort* bs = sh.p1.Bs[buf];
#pragma unroll
      for (int ks = 0; ks < 2; ++ks) {
        short8 af[2], bf[2];
#pragma unroll
        for (int m = 0; m < 2; ++m) {
          int r = wm * 32 + m * 16 + (lane & 15);
          af[m] = *(const short8*)(as + r * LDA + ks * 32 + (lane >> 4) * 8);
        }
#pragma unroll
        for (int n = 0; n < 2; ++n) {
          int cdx = wn * 32 + n * 16 + (lane & 15);
          bf[n] = *(const short8*)(bs + cdx * LDA + ks * 32 + (lane >> 4) * 8);
        }
#pragma unroll
        for (int m = 0; m < 2; ++m)
#pragma unroll
          for (int n = 0; n < 2; ++n)
            acc[m][n] = __builtin_amdgcn_mfma_f32_16x16x32_bf16(af[m], bf[n], acc[m][n], 0, 0, 0);
      }
    };

    loadT(0);
    writeT(0, 0);
    __syncthreads();
    int cur = 0;
    for (int kt = 0; kt < NK; ++kt) {
      if (kt + 1 < NK) loadT(kt + 1);
      mma(cur);
      if (kt + 1 < NK) writeT(cur ^ 1, kt + 1);
      __syncthreads();
      cur ^= 1;
    }

    // C/D layout: col = lane&15, row = (lane>>4)*4 + reg   [m89-verified]
#pragma unroll
    for (int m = 0; m < 2; ++m)
#pragma unroll
      for (int n = 0; n < 2; ++n) {
        int colg = n0 + wn * 32 + n * 16 + (lane & 15);
        float bval = b1[colg];
#pragma unroll
        for (int r = 0; r < 4; ++r) {
          int rowg = m0 + wm * 32 + m * 16 + (lane >> 4) * 4 + r;
          h1[(size_t)rowg * 256 + colg] = f2bf(fmaxf(acc[m][n][r] + bval, 0.f));
        }
      }
  }

  // h1 visible to all XCDs, then grid-wide barrier
  __threadfence();
  cg::this_grid().sync();

  // ======================= Phase 2 =======================
  {
    constexpr int NK = 4;   // K = 256, BK = 64
    const int m0 = blockIdx.x * 16;   // 512 blocks x 16 rows

    for (int i = tid; i < 1280; i += 256) sh.p2.W3s[i] = W3[i];

    const bool ldA = tid < 128;
    const int ar = tid >> 3, asl = tid & 7;          // A: 16 rows x 8 slots

    uint4 av;
    float4 bw[8];
    auto loadT = [&](int kt) {
      const int k0 = kt * 64;
      if (ldA) av = *(const uint4*)(h1 + (size_t)(m0 + ar) * 256 + k0 + asl * 8);
#pragma unroll
      for (int c = 0; c < 8; ++c) {
        const int flat = c * 256 + tid, r = flat >> 4, sl = flat & 15;
        bw[c] = *(const float4*)(W2 + (size_t)r * 256 + k0 + sl * 4);
      }
    };
    auto writeT = [&](int buf) {
      if (ldA) *(uint4*)(sh.p2.As[buf] + ar * LDA + asl * 8) = av;
#pragma unroll
      for (int c = 0; c < 8; ++c) {
        const int flat = c * 256 + tid, r = flat >> 4, sl = flat & 15;
        *(uint2*)(sh.p2.Bs[buf] + r * LDA + sl * 4) =
            pack4(bw[c].x, bw[c].y, bw[c].z, bw[c].w);
      }
    };

    f32x4 acc[2];
#pragma unroll
    for (int n = 0; n < 2; ++n) {
      f32x4 z = {0.f, 0.f, 0.f, 0.f};
      acc[n] = z;
    }

    auto mma = [&](int buf) {
#pragma unroll
      for (int ks = 0; ks < 2; ++ks) {
        short8 af = *(const short8*)(sh.p2.As[buf] + (lane & 15) * LDA + ks * 32 + (lane >> 4) * 8);
#pragma unroll
        for (int n = 0; n < 2; ++n) {
          int cdx = w * 32 + n * 16 + (lane & 15);
          short8 bf = *(const short8*)(sh.p2.Bs[buf] + cdx * LDA + ks * 32 + (lane >> 4) * 8);
          acc[n] = __builtin_amdgcn_mfma_f32_16x16x32_bf16(af, bf, acc[n], 0, 0, 0);
        }
      }
    };

    loadT(0);
    writeT(0);
    __syncthreads();
    int cur = 0;
#pragma unroll
    for (int kt = 0; kt < NK; ++kt) {
      if (kt + 1 < NK) loadT(kt + 1);
      mma(cur);
      if (kt + 1 < NK) writeT(cur ^ 1);
      __syncthreads();
      cur ^= 1;
    }

    // h2 tile -> LDS f32 (bias + relu); wave w owns cols w*32..w*32+31
#pragma unroll
    for (int n = 0; n < 2; ++n) {
      const int col = w * 32 + n * 16 + (lane & 15);
      const float bval = b2[col];
#pragma unroll
      for (int r = 0; r < 4; ++r)
        sh.p2.h2f[(lane >> 4) * 4 + r][col] = fmaxf(acc[n][r] + bval, 0.f);
    }
    __syncthreads();

    // head: 16 rows x 16 partials; k = e*16 + p
    {
      const int r = tid >> 4, p = tid & 15;
      float a10[10];
#pragma unroll
      for (int n = 0; n < 10; ++n) a10[n] = 0.f;
#pragma unroll
      for (int e = 0; e < 8; ++e) {
        const int k = e * 16 + p;
        const float hv = sh.p2.h2f[r][k];
#pragma unroll
        for (int n = 0; n < 10; ++n) a10[n] = fmaf(hv, sh.p2.W3s[n * 128 + k], a10[n]);
      }
#pragma unroll
      for (int n = 0; n < 10; ++n) {
        a10[n] += __shfl_xor(a10[n], 1);
        a10[n] += __shfl_xor(a10[n], 2);
        a10[n] += __shfl_xor(a10[n], 4);
        a10[n] += __shfl_xor(a10[n], 8);
      }
      if (p == 0) {
#pragma unroll
        for (int n = 0; n < 10; ++n) a10[n] += b3[n];
        float mx = a10[0];
#pragma unroll
        for (int n = 1; n < 10; ++n) mx = fmaxf(mx, a10[n]);
        float s = 0.f;
#pragma unroll
        for (int n = 0; n < 10; ++n) s += __expf(a10[n] - mx);
        const float lse = mx + __logf(s);
        float* po = out + (size_t)(m0 + r) * 10;
#pragma unroll
        for (int n = 0; n < 10; ++n) po[n] = a10[n] - lse;
      }
    }
  }
}

// ---------------------------------------------------------------------------
extern "C" void kernel_launch(void* const* d_in, const int* in_sizes, int n_in,
                              void* d_out, int out_size, void* d_ws, size_t ws_size,
                              hipStream_t stream) {
  const float* x  = (const float*)d_in[0];   // (8192,1,28,28)
  // d_in[1] = params: provably unused (diagonal phases cancel in |amp|^2)
  const float* W1 = (const float*)d_in[2];
  const float* b1 = (const float*)d_in[3];
  const float* W2 = (const float*)d_in[4];
  const float* b2 = (const float*)d_in[5];
  const float* W3 = (const float*)d_in[6];
  const float* b3 = (const float*)d_in[7];
  float* out = (float*)d_out;

  ushort* h1 = (ushort*)d_ws;                 // 8192 x 256 bf16 (4.2 MB)

  void* args[] = {(void*)&x, (void*)&W1, (void*)&b1, (void*)&W2, (void*)&b2,
                  (void*)&W3, (void*)&b3, (void*)&h1, (void*)&out};
  hipLaunchCooperativeKernel((void*)fused_all, dim3(512), dim3(256),
                             args, 0, stream);
}

// Round 11
// 29.923 us; speedup vs baseline: 4.6774x; 4.6774x over previous
//
#include <hip/hip_runtime.h>
#include <stdint.h>

typedef __attribute__((ext_vector_type(8))) short short8;
typedef __attribute__((ext_vector_type(4))) float f32x4;

#define DEVI __device__ __forceinline__

DEVI ushort f2bf(float f) {
  union { float f; uint32_t u; } v; v.f = f;
  uint32_t r = v.u + 0x7fffu + ((v.u >> 16) & 1u);
  return (ushort)(r >> 16);
}

// HW packed f32->bf16 (RTNE, identical rounding to f2bf): 1 inst per 2 elems.
DEVI uint32_t cvtpk(float lo, float hi) {
  uint32_t r;
  asm("v_cvt_pk_bf16_f32 %0, %1, %2" : "=v"(r) : "v"(lo), "v"(hi));
  return r;
}
DEVI uint2 pack4(float a, float b, float c, float d) {
  uint2 o; o.x = cvtpk(a, b); o.y = cvtpk(c, d);
  return o;
}

// ---------------------------------------------------------------------------
// Quantum sim collapses analytically (params provably dead):
//   feats per 2x2 patch (v0,v1,v2,v3) = [cos v0, cos v1, cos v0*cos v2,
//   cos v1*cos v3]; CNOT chains = linear bit map; RZ phases cancel in |.|^2.
//
// Kernel 1: h1 = relu(feats(x) @ W1^T + b1), cos + W1 cast fused into
// staging (no prep kernel). R9 champion except BK 64->128: 7 K-steps instead
// of 13 — 2x compute per step to hide the ~600cyc load latency, half the
// barriers. K virtually padded to 896 (zero A for q>=196, zero B for k>=784).
// LDS 69.6 KB -> still 2 blocks/CU. 512 blocks.
// ---------------------------------------------------------------------------
__global__ __launch_bounds__(256) void gemm1_fused(
    const float* __restrict__ x, const float* __restrict__ W1,
    const float* __restrict__ b1, ushort* __restrict__ h1) {
  constexpr int LDA = 136;  // 272B row stride: 4-bank walk -> <=2-way reads
  constexpr int NK = 7;     // K = 896 virtual (784 real + pad)
  __shared__ ushort As[2][64 * LDA];   // 34816 B
  __shared__ ushort Bs[2][64 * LDA];   // 34816 B  (69632 total)

  const int tid = threadIdx.x;
  const int lane = tid & 63;
  const int w = tid >> 6, wm = w >> 1, wn = w & 1;
  const int bm = blockIdx.x & 127, bn = blockIdx.x >> 7;
  const int m0 = bm * 64, n0 = bn * 64;

  const int srow = tid >> 4;        // 0..15: sub-row in each 16-row group
  const int pl = tid & 15;          // patch slot within half-k-tile
  const int kc4 = pl * 4;           // B k-offset within half

  // two halves per K-step (each half identical to the old BK=64 staging)
  float2 atop[2][4], abot[2][4];    // [half][row-group]
  float4 bw[2][4];

  f32x4 acc[2][2];
#pragma unroll
  for (int m = 0; m < 2; ++m)
#pragma unroll
    for (int n = 0; n < 2; ++n) {
      f32x4 z = {0.f, 0.f, 0.f, 0.f};
      acc[m][n] = z;
    }

  auto loadT = [&](int kt) {
#pragma unroll
    for (int h = 0; h < 2; ++h) {
      const int q = (kt * 2 + h) * 16 + pl;     // patch index
      if (q < 196) {
        const int i = q / 14, j = q - i * 14;
        const float* px = x + i * 56 + j * 2;
#pragma unroll
        for (int c = 0; c < 4; ++c) {
          const float* p = px + (size_t)(m0 + c * 16 + srow) * 784;
          atop[h][c] = *(const float2*)p;
          abot[h][c] = *(const float2*)(p + 28);
        }
      }
      const int k0 = (kt * 2 + h) * 64;
      if (k0 + kc4 < 784) {
#pragma unroll
        for (int c = 0; c < 4; ++c)
          bw[h][c] = *(const float4*)(W1 + (size_t)(n0 + c * 16 + srow) * 784 + k0 + kc4);
      } else {
#pragma unroll
        for (int c = 0; c < 4; ++c) bw[h][c] = make_float4(0.f, 0.f, 0.f, 0.f);
      }
    }
  };

  auto writeT = [&](int buf, int kt) {
    ushort* as = As[buf];
    ushort* bs = Bs[buf];
#pragma unroll
    for (int h = 0; h < 2; ++h) {
      const int q = (kt * 2 + h) * 16 + pl;
      if (q < 196) {
#pragma unroll
        for (int c = 0; c < 4; ++c) {
          float c0 = __cosf(atop[h][c].x), c1 = __cosf(atop[h][c].y);
          float c2 = __cosf(abot[h][c].x), c3 = __cosf(abot[h][c].y);
          *(uint2*)(as + (c * 16 + srow) * LDA + h * 64 + pl * 4) =
              pack4(c0, c1, c0 * c2, c1 * c3);
        }
      } else {
        uint2 z; z.x = 0; z.y = 0;
#pragma unroll
        for (int c = 0; c < 4; ++c)
          *(uint2*)(as + (c * 16 + srow) * LDA + h * 64 + pl * 4) = z;
      }
#pragma unroll
      for (int c = 0; c < 4; ++c)
        *(uint2*)(bs + (c * 16 + srow) * LDA + h * 64 + kc4) =
            pack4(bw[h][c].x, bw[h][c].y, bw[h][c].z, bw[h][c].w);
    }
  };

  auto mma = [&](int buf) {
    const ushort* as = As[buf];
    const ushort* bs = Bs[buf];
#pragma unroll
    for (int ks = 0; ks < 4; ++ks) {
      short8 af[2], bf[2];
#pragma unroll
      for (int m = 0; m < 2; ++m) {
        int r = wm * 32 + m * 16 + (lane & 15);
        af[m] = *(const short8*)(as + r * LDA + ks * 32 + (lane >> 4) * 8);
      }
#pragma unroll
      for (int n = 0; n < 2; ++n) {
        int cdx = wn * 32 + n * 16 + (lane & 15);
        bf[n] = *(const short8*)(bs + cdx * LDA + ks * 32 + (lane >> 4) * 8);
      }
#pragma unroll
      for (int m = 0; m < 2; ++m)
#pragma unroll
        for (int n = 0; n < 2; ++n)
          acc[m][n] = __builtin_amdgcn_mfma_f32_16x16x32_bf16(af[m], bf[n], acc[m][n], 0, 0, 0);
    }
  };

  loadT(0);
  writeT(0, 0);
  __syncthreads();
  int cur = 0;
  for (int kt = 0; kt < NK; ++kt) {
    if (kt + 1 < NK) loadT(kt + 1);
    mma(cur);
    if (kt + 1 < NK) writeT(cur ^ 1, kt + 1);
    __syncthreads();
    cur ^= 1;
  }

  // C/D layout: col = lane&15, row = (lane>>4)*4 + reg   [m89-verified]
#pragma unroll
  for (int m = 0; m < 2; ++m)
#pragma unroll
    for (int n = 0; n < 2; ++n) {
      int colg = n0 + wn * 32 + n * 16 + (lane & 15);
      float bval = b1[colg];
#pragma unroll
      for (int r = 0; r < 4; ++r) {
        int rowg = m0 + wm * 32 + m * 16 + (lane >> 4) * 4 + r;
        h1[(size_t)rowg * 256 + colg] = f2bf(fmaxf(acc[m][n][r] + bval, 0.f));
      }
    }
}

// ---------------------------------------------------------------------------
// Kernel 2 (R9 champion, unchanged): h2 = relu(h1 @ W2^T + b2) (W2 cast in
// staging via cvt_pk), h2 in LDS; then logits = h2 @ W3^T + b3, log_softmax.
// BM=32, BN=128 (full N), K=256 in 4 dbuf steps; 256 blocks.
// ---------------------------------------------------------------------------
__global__ __launch_bounds__(256) void gemm2_head(
    const ushort* __restrict__ h1, const float* __restrict__ W2,
    const float* __restrict__ b2, const float* __restrict__ W3,
    const float* __restrict__ b3, float* __restrict__ out) {
  constexpr int LDA = 72;
  constexpr int NK = 4;   // K = 256, BK = 64
  __shared__ ushort As[2][32 * LDA];
  __shared__ ushort Bs[2][128 * LDA];
  __shared__ float h2f[32][132];
  __shared__ float W3s[1280];

  const int tid = threadIdx.x;
  const int lane = tid & 63;
  const int w = tid >> 6, wm = w >> 1, wn = w & 1;
  const int m0 = blockIdx.x * 32;

  for (int i = tid; i < 1280; i += 256) W3s[i] = W3[i];

  const int ar = tid >> 3, asl = tid & 7;          // A: 32 rows x 8 slots
  const int br = tid >> 4, kc4 = (tid & 15) * 4;   // B: rows c*16+br

  uint4 av;
  float4 bw[8];

  auto loadT = [&](int kt) {
    const int k0 = kt * 64;
    av = *(const uint4*)(h1 + (size_t)(m0 + ar) * 256 + k0 + asl * 8);
#pragma unroll
    for (int c = 0; c < 8; ++c)
      bw[c] = *(const float4*)(W2 + (size_t)(c * 16 + br) * 256 + k0 + kc4);
  };
  auto writeT = [&](int buf) {
    *(uint4*)(As[buf] + ar * LDA + asl * 8) = av;
#pragma unroll
    for (int c = 0; c < 8; ++c)
      *(uint2*)(Bs[buf] + (c * 16 + br) * LDA + kc4) =
          pack4(bw[c].x, bw[c].y, bw[c].z, bw[c].w);
  };

  f32x4 acc[4];
#pragma unroll
  for (int n = 0; n < 4; ++n) {
    f32x4 z = {0.f, 0.f, 0.f, 0.f};
    acc[n] = z;
  }

  auto mma = [&](int buf) {
    const ushort* as = As[buf];
    const ushort* bs = Bs[buf];
#pragma unroll
    for (int ks = 0; ks < 2; ++ks) {
      int r = wm * 16 + (lane & 15);
      short8 af = *(const short8*)(as + r * LDA + ks * 32 + (lane >> 4) * 8);
#pragma unroll
      for (int n = 0; n < 4; ++n) {
        int cdx = wn * 64 + n * 16 + (lane & 15);
        short8 bf = *(const short8*)(bs + cdx * LDA + ks * 32 + (lane >> 4) * 8);
        acc[n] = __builtin_amdgcn_mfma_f32_16x16x32_bf16(af, bf, acc[n], 0, 0, 0);
      }
    }
  };

  loadT(0);
  writeT(0);
  __syncthreads();
  int cur = 0;
  for (int kt = 0; kt < NK; ++kt) {
    if (kt + 1 < NK) loadT(kt + 1);
    mma(cur);
    if (kt + 1 < NK) writeT(cur ^ 1);
    __syncthreads();
    cur ^= 1;
  }

  // h2 tile -> LDS with bias + relu
#pragma unroll
  for (int n = 0; n < 4; ++n) {
    int col = wn * 64 + n * 16 + (lane & 15);
    float bval = b2[col];
#pragma unroll
    for (int r = 0; r < 4; ++r)
      h2f[wm * 16 + (lane >> 4) * 4 + r][col] = fmaxf(acc[n][r] + bval, 0.f);
  }
  __syncthreads();

  // head: row r = tid>>3 (32 rows), partial p = tid&7 over k = e*8+p
  {
    int r = tid >> 3, p = tid & 7;
    float a10[10];
#pragma unroll
    for (int n = 0; n < 10; ++n) a10[n] = 0.f;
#pragma unroll
    for (int e = 0; e < 16; ++e) {
      int k = e * 8 + p;
      float hv = h2f[r][k];
#pragma unroll
      for (int n = 0; n < 10; ++n) a10[n] = fmaf(hv, W3s[n * 128 + k], a10[n]);
    }
#pragma unroll
    for (int n = 0; n < 10; ++n) {
      a10[n] += __shfl_xor(a10[n], 1);
      a10[n] += __shfl_xor(a10[n], 2);
      a10[n] += __shfl_xor(a10[n], 4);
    }
    if (p == 0) {
#pragma unroll
      for (int n = 0; n < 10; ++n) a10[n] += b3[n];
      float mx = a10[0];
#pragma unroll
      for (int n = 1; n < 10; ++n) mx = fmaxf(mx, a10[n]);
      float s = 0.f;
#pragma unroll
      for (int n = 0; n < 10; ++n) s += __expf(a10[n] - mx);
      float lse = mx + __logf(s);
      float* po = out + (size_t)(m0 + r) * 10;
#pragma unroll
      for (int n = 0; n < 10; ++n) po[n] = a10[n] - lse;
    }
  }
}

// ---------------------------------------------------------------------------
extern "C" void kernel_launch(void* const* d_in, const int* in_sizes, int n_in,
                              void* d_out, int out_size, void* d_ws, size_t ws_size,
                              hipStream_t stream) {
  const float* x  = (const float*)d_in[0];   // (8192,1,28,28)
  // d_in[1] = params: provably unused (diagonal phases cancel in |amp|^2)
  const float* W1 = (const float*)d_in[2];
  const float* b1 = (const float*)d_in[3];
  const float* W2 = (const float*)d_in[4];
  const float* b2 = (const float*)d_in[5];
  const float* W3 = (const float*)d_in[6];
  const float* b3 = (const float*)d_in[7];
  float* out = (float*)d_out;

  ushort* h1 = (ushort*)d_ws;                 // 8192 x 256 bf16 (4.2 MB)

  hipLaunchKernelGGL(gemm1_fused, dim3(512), dim3(256), 0, stream, x, W1, b1, h1);
  hipLaunchKernelGGL(gemm2_head, dim3(256), dim3(256), 0, stream, h1, W2, b2, W3, b3, out);
}

// Round 12
// 28.180 us; speedup vs baseline: 4.9667x; 1.0618x over previous
//
#include <hip/hip_runtime.h>
#include <stdint.h>

typedef __attribute__((ext_vector_type(8))) short short8;
typedef __attribute__((ext_vector_type(4))) float f32x4;

#define DEVI __device__ __forceinline__

DEVI ushort f2bf(float f) {
  union { float f; uint32_t u; } v; v.f = f;
  uint32_t r = v.u + 0x7fffu + ((v.u >> 16) & 1u);
  return (ushort)(r >> 16);
}

// HW packed f32->bf16 (RTNE, identical rounding to f2bf): 1 inst per 2 elems.
DEVI uint32_t cvtpk(float lo, float hi) {
  uint32_t r;
  asm("v_cvt_pk_bf16_f32 %0, %1, %2" : "=v"(r) : "v"(lo), "v"(hi));
  return r;
}
DEVI uint2 pack4(float a, float b, float c, float d) {
  uint2 o; o.x = cvtpk(a, b); o.y = cvtpk(c, d);
  return o;
}

// ---------------------------------------------------------------------------
// Quantum sim collapses analytically (params provably dead):
//   feats per 2x2 patch (v0,v1,v2,v3) = [cos v0, cos v1, cos v0*cos v2,
//   cos v1*cos v3]; CNOT chains = linear bit map; RZ phases cancel in |.|^2.
//
// Kernel 1: h1 = relu(feats(x) @ W1^T + b1), cos + W1 cast fused into
// staging. Champion geometry (BM=BN=64, BK=64, dbuf, 512 blocks) but
// 512 THREADS / 8 waves per block (2x4 wave grid): same chip-wide work &
// redundancy, half the staging per thread, 4 waves/SIMD instead of 2 —
// pure TLP to cover the load latency that R6's counters showed exposed.
// ---------------------------------------------------------------------------
__global__ __launch_bounds__(512) void gemm1_fused(
    const float* __restrict__ x, const float* __restrict__ W1,
    const float* __restrict__ b1, ushort* __restrict__ h1) {
  constexpr int LDA = 72;   // 144B row stride -> <=2-way b128 reads (free)
  constexpr int NK = 13;    // K = 832 (784 + pad)
  __shared__ ushort As[2][64 * LDA];   // 18432 B
  __shared__ ushort Bs[2][64 * LDA];   // 18432 B  (36864 total)

  const int tid = threadIdx.x;
  const int lane = tid & 63;
  const int w = tid >> 6;              // 8 waves: wm in {0,1}, wn in {0..3}
  const int wm = w >> 2, wn = w & 3;
  const int bm = blockIdx.x & 127, bn = blockIdx.x >> 7;
  const int m0 = bm * 64, n0 = bn * 64;

  const int srow = tid >> 4;        // 0..31: staging row within 32-row group
  const int pl = tid & 15;          // patch slot / float4 slot
  const int kc4 = pl * 4;

  float2 atop[2], abot[2];          // staged x (2 rows, 1 patch)
  float4 bw[2];                     // staged W1 (2 rows, 4 cols)

  f32x4 acc[2];                     // wave tile 32 x 16 (MF=2, NF=1)
#pragma unroll
  for (int m = 0; m < 2; ++m) {
    f32x4 z = {0.f, 0.f, 0.f, 0.f};
    acc[m] = z;
  }

  auto loadT = [&](int kt) {
    const int q = kt * 16 + pl;                 // patch index
    if (q < 196) {
      const int i = q / 14, j = q - i * 14;
      const float* px = x + i * 56 + j * 2;
#pragma unroll
      for (int c = 0; c < 2; ++c) {
        const float* p = px + (size_t)(m0 + c * 32 + srow) * 784;
        atop[c] = *(const float2*)p;
        abot[c] = *(const float2*)(p + 28);
      }
    }
    const int k0 = kt * 64;
    if (k0 + kc4 < 784) {
#pragma unroll
      for (int c = 0; c < 2; ++c)
        bw[c] = *(const float4*)(W1 + (size_t)(n0 + c * 32 + srow) * 784 + k0 + kc4);
    } else {
#pragma unroll
      for (int c = 0; c < 2; ++c) bw[c] = make_float4(0.f, 0.f, 0.f, 0.f);
    }
  };

  auto writeT = [&](int buf, int kt) {
    const int q = kt * 16 + pl;
    ushort* as = As[buf];
    ushort* bs = Bs[buf];
    if (q < 196) {
#pragma unroll
      for (int c = 0; c < 2; ++c) {
        float c0 = __cosf(atop[c].x), c1 = __cosf(atop[c].y);
        float c2 = __cosf(abot[c].x), c3 = __cosf(abot[c].y);
        *(uint2*)(as + (c * 32 + srow) * LDA + pl * 4) =
            pack4(c0, c1, c0 * c2, c1 * c3);
      }
    } else {
      uint2 z; z.x = 0; z.y = 0;
#pragma unroll
      for (int c = 0; c < 2; ++c)
        *(uint2*)(as + (c * 32 + srow) * LDA + pl * 4) = z;
    }
#pragma unroll
    for (int c = 0; c < 2; ++c)
      *(uint2*)(bs + (c * 32 + srow) * LDA + kc4) =
          pack4(bw[c].x, bw[c].y, bw[c].z, bw[c].w);
  };

  auto mma = [&](int buf) {
    const ushort* as = As[buf];
    const ushort* bs = Bs[buf];
#pragma unroll
    for (int ks = 0; ks < 2; ++ks) {
      short8 af[2];
#pragma unroll
      for (int m = 0; m < 2; ++m) {
        int r = wm * 32 + m * 16 + (lane & 15);
        af[m] = *(const short8*)(as + r * LDA + ks * 32 + (lane >> 4) * 8);
      }
      int cdx = wn * 16 + (lane & 15);
      short8 bf = *(const short8*)(bs + cdx * LDA + ks * 32 + (lane >> 4) * 8);
#pragma unroll
      for (int m = 0; m < 2; ++m)
        acc[m] = __builtin_amdgcn_mfma_f32_16x16x32_bf16(af[m], bf, acc[m], 0, 0, 0);
    }
  };

  loadT(0);
  writeT(0, 0);
  __syncthreads();
  int cur = 0;
  for (int kt = 0; kt < NK; ++kt) {
    if (kt + 1 < NK) loadT(kt + 1);
    mma(cur);
    if (kt + 1 < NK) writeT(cur ^ 1, kt + 1);
    __syncthreads();
    cur ^= 1;
  }

  // C/D layout: col = lane&15, row = (lane>>4)*4 + reg   [m89-verified]
#pragma unroll
  for (int m = 0; m < 2; ++m) {
    const int colg = n0 + wn * 16 + (lane & 15);
    const float bval = b1[colg];
#pragma unroll
    for (int r = 0; r < 4; ++r) {
      const int rowg = m0 + wm * 32 + m * 16 + (lane >> 4) * 4 + r;
      h1[(size_t)rowg * 256 + colg] = f2bf(fmaxf(acc[m][r] + bval, 0.f));
    }
  }
}

// ---------------------------------------------------------------------------
// Kernel 2 (R9 champion, unchanged): h2 = relu(h1 @ W2^T + b2) (W2 cast in
// staging via cvt_pk), h2 in LDS; then logits = h2 @ W3^T + b3, log_softmax.
// BM=32, BN=128 (full N), K=256 in 4 dbuf steps; 256 blocks.
// ---------------------------------------------------------------------------
__global__ __launch_bounds__(256) void gemm2_head(
    const ushort* __restrict__ h1, const float* __restrict__ W2,
    const float* __restrict__ b2, const float* __restrict__ W3,
    const float* __restrict__ b3, float* __restrict__ out) {
  constexpr int LDA = 72;
  constexpr int NK = 4;   // K = 256, BK = 64
  __shared__ ushort As[2][32 * LDA];
  __shared__ ushort Bs[2][128 * LDA];
  __shared__ float h2f[32][132];
  __shared__ float W3s[1280];

  const int tid = threadIdx.x;
  const int lane = tid & 63;
  const int w = tid >> 6, wm = w >> 1, wn = w & 1;
  const int m0 = blockIdx.x * 32;

  for (int i = tid; i < 1280; i += 256) W3s[i] = W3[i];

  const int ar = tid >> 3, asl = tid & 7;          // A: 32 rows x 8 slots
  const int br = tid >> 4, kc4 = (tid & 15) * 4;   // B: rows c*16+br

  uint4 av;
  float4 bw[8];

  auto loadT = [&](int kt) {
    const int k0 = kt * 64;
    av = *(const uint4*)(h1 + (size_t)(m0 + ar) * 256 + k0 + asl * 8);
#pragma unroll
    for (int c = 0; c < 8; ++c)
      bw[c] = *(const float4*)(W2 + (size_t)(c * 16 + br) * 256 + k0 + kc4);
  };
  auto writeT = [&](int buf) {
    *(uint4*)(As[buf] + ar * LDA + asl * 8) = av;
#pragma unroll
    for (int c = 0; c < 8; ++c)
      *(uint2*)(Bs[buf] + (c * 16 + br) * LDA + kc4) =
          pack4(bw[c].x, bw[c].y, bw[c].z, bw[c].w);
  };

  f32x4 acc[4];
#pragma unroll
  for (int n = 0; n < 4; ++n) {
    f32x4 z = {0.f, 0.f, 0.f, 0.f};
    acc[n] = z;
  }

  auto mma = [&](int buf) {
    const ushort* as = As[buf];
    const ushort* bs = Bs[buf];
#pragma unroll
    for (int ks = 0; ks < 2; ++ks) {
      int r = wm * 16 + (lane & 15);
      short8 af = *(const short8*)(as + r * LDA + ks * 32 + (lane >> 4) * 8);
#pragma unroll
      for (int n = 0; n < 4; ++n) {
        int cdx = wn * 64 + n * 16 + (lane & 15);
        short8 bf = *(const short8*)(bs + cdx * LDA + ks * 32 + (lane >> 4) * 8);
        acc[n] = __builtin_amdgcn_mfma_f32_16x16x32_bf16(af, bf, acc[n], 0, 0, 0);
      }
    }
  };

  loadT(0);
  writeT(0);
  __syncthreads();
  int cur = 0;
  for (int kt = 0; kt < NK; ++kt) {
    if (kt + 1 < NK) loadT(kt + 1);
    mma(cur);
    if (kt + 1 < NK) writeT(cur ^ 1);
    __syncthreads();
    cur ^= 1;
  }

  // h2 tile -> LDS with bias + relu
#pragma unroll
  for (int n = 0; n < 4; ++n) {
    int col = wn * 64 + n * 16 + (lane & 15);
    float bval = b2[col];
#pragma unroll
    for (int r = 0; r < 4; ++r)
      h2f[wm * 16 + (lane >> 4) * 4 + r][col] = fmaxf(acc[n][r] + bval, 0.f);
  }
  __syncthreads();

  // head: row r = tid>>3 (32 rows), partial p = tid&7 over k = e*8+p
  {
    int r = tid >> 3, p = tid & 7;
    float a10[10];
#pragma unroll
    for (int n = 0; n < 10; ++n) a10[n] = 0.f;
#pragma unroll
    for (int e = 0; e < 16; ++e) {
      int k = e * 8 + p;
      float hv = h2f[r][k];
#pragma unroll
      for (int n = 0; n < 10; ++n) a10[n] = fmaf(hv, W3s[n * 128 + k], a10[n]);
    }
#pragma unroll
    for (int n = 0; n < 10; ++n) {
      a10[n] += __shfl_xor(a10[n], 1);
      a10[n] += __shfl_xor(a10[n], 2);
      a10[n] += __shfl_xor(a10[n], 4);
    }
    if (p == 0) {
#pragma unroll
      for (int n = 0; n < 10; ++n) a10[n] += b3[n];
      float mx = a10[0];
#pragma unroll
      for (int n = 1; n < 10; ++n) mx = fmaxf(mx, a10[n]);
      float s = 0.f;
#pragma unroll
      for (int n = 0; n < 10; ++n) s += __expf(a10[n] - mx);
      float lse = mx + __logf(s);
      float* po = out + (size_t)(m0 + r) * 10;
#pragma unroll
      for (int n = 0; n < 10; ++n) po[n] = a10[n] - lse;
    }
  }
}

// ---------------------------------------------------------------------------
extern "C" void kernel_launch(void* const* d_in, const int* in_sizes, int n_in,
                              void* d_out, int out_size, void* d_ws, size_t ws_size,
                              hipStream_t stream) {
  const float* x  = (const float*)d_in[0];   // (8192,1,28,28)
  // d_in[1] = params: provably unused (diagonal phases cancel in |amp|^2)
  const float* W1 = (const float*)d_in[2];
  const float* b1 = (const float*)d_in[3];
  const float* W2 = (const float*)d_in[4];
  const float* b2 = (const float*)d_in[5];
  const float* W3 = (const float*)d_in[6];
  const float* b3 = (const float*)d_in[7];
  float* out = (float*)d_out;

  ushort* h1 = (ushort*)d_ws;                 // 8192 x 256 bf16 (4.2 MB)

  hipLaunchKernelGGL(gemm1_fused, dim3(512), dim3(512), 0, stream, x, W1, b1, h1);
  hipLaunchKernelGGL(gemm2_head, dim3(256), dim3(256), 0, stream, h1, W2, b2, W3, b3, out);
}